// Round 1
// baseline (111.729 us; speedup 1.0000x reference)
//
#include <hip/hip_runtime.h>
#include <hip/hip_bf16.h>

#define VOCABSZ 50257
#define BASEDIM 64
#define ND 16
#define NTOK (16 * 8192)
#define NBLK_PER_DOM 32

typedef __attribute__((ext_vector_type(8))) short short8;
typedef __attribute__((ext_vector_type(4))) float f32x4;

__device__ __forceinline__ short f2bf(float f) {
    union { float f; unsigned u; } v; v.f = f;
    unsigned r = (v.u + 0x7FFFu + ((v.u >> 16) & 1u)) >> 16;  // RNE f32->bf16
    return (short)r;
}

// Kernel A: per-token domain bucketing (two-level atomics) + base embedding
// write for UNASSIGNED tokens (assigned tokens are written by kernel B).
__global__ __launch_bounds__(256) void k_bucket_base(
    const int* __restrict__ x, const int* __restrict__ tdom,
    const float* __restrict__ emb, float* __restrict__ out,
    int* __restrict__ g_cnt, int* __restrict__ bucket, int cap)
{
    __shared__ int sm_d[256];
    __shared__ int sm_x[256];
    __shared__ int sm_cnt[ND];
    __shared__ int sm_base[ND];

    const int lt = threadIdx.x;
    const int t0 = blockIdx.x * 256;
    const int t  = t0 + lt;

    if (lt < ND) sm_cnt[lt] = 0;
    __syncthreads();

    const int xt = x[t];
    const int d  = tdom[xt];
    sm_x[lt] = xt;
    sm_d[lt] = d;
    int pos = -1;
    if (d < ND) pos = atomicAdd(&sm_cnt[d], 1);
    __syncthreads();

    if (lt < ND) sm_base[lt] = atomicAdd(&g_cnt[lt], sm_cnt[lt]);
    __syncthreads();

    if (d < ND) {
        const int gp = sm_base[d] + pos;
        if (gp < cap) bucket[d * cap + gp] = t;
    }

    // Phase 2: 16-lane groups write 256B rows for unassigned tokens.
    const int g = lt >> 4, l16 = lt & 15;
    const float4* embv = (const float4*)emb;
    float4* outv = (float4*)out;
    #pragma unroll
    for (int it = 0; it < 16; ++it) {
        const int li = it * 16 + g;
        if (sm_d[li] >= ND) {
            outv[(size_t)(t0 + li) * 16 + l16] =
                embv[(size_t)sm_x[li] * 16 + l16];
        }
    }
}

// Kernel B: per-domain MLP correction via MFMA. Each block: one domain,
// weights as register bf16 fragments. Each wave: batches of 16 tokens.
__global__ __launch_bounds__(256) void k_domain(
    const int* __restrict__ x, const float* __restrict__ emb,
    const float* __restrict__ W1, const float* __restrict__ W2,
    const int* __restrict__ g_cnt, const int* __restrict__ bucket,
    int cap, float* __restrict__ out)
{
    const int blk   = blockIdx.x;
    const int d     = blk >> 5;            // NBLK_PER_DOM = 32
    const int chunk = blk & 31;
    int cnt = g_cnt[d];
    if (cnt > cap) cnt = cap;

    const int wave = threadIdx.x >> 6;
    const int lane = threadIdx.x & 63;
    const int kr   = (lane >> 4) * 8;      // k-octet base within a 32-K tile
    const int nco  = lane & 15;

    // --- Load W1[d], W2[d] as MFMA B-fragments (bf16), 64 VGPRs total ---
    const float* w1 = W1 + (size_t)d * 4096;
    const float* w2 = W2 + (size_t)d * 4096;
    short8 fw1[8], fw2[8];
    #pragma unroll
    for (int kt = 0; kt < 2; ++kt) {
        #pragma unroll
        for (int nt = 0; nt < 4; ++nt) {
            short8 a, b;
            #pragma unroll
            for (int i = 0; i < 8; ++i) {
                const int k = kt * 32 + kr + i;
                const int n = nt * 16 + nco;
                a[i] = f2bf(w1[k * 64 + n]);
                b[i] = f2bf(w2[k * 64 + n]);
            }
            fw1[kt * 4 + nt] = a;
            fw2[kt * 4 + nt] = b;
        }
    }

    // Per-wave hid staging buffer: [16 rows][stride 72 bf16] (pad kills 32-way
    // bank conflicts on the b128 re-read; 144B row stride keeps 16B alignment).
    __shared__ __align__(16) short sm_hid[4][16 * 72];
    short* hidb = &sm_hid[wave][0];

    const int* buck = bucket + (size_t)d * cap;

    for (int base = chunk * 64; base < cnt; base += NBLK_PER_DOM * 64) {
        const int s0 = base + wave * 16;
        int rem = cnt - s0;
        if (rem <= 0) continue;           // per-wave; no barriers in loop
        if (rem > 16) rem = 16;

        // --- Gather H A-fragments: lane row m = lane&15 ---
        const int m_idx = s0 + (nco < rem ? nco : rem - 1);
        const int tm = buck[m_idx];
        const float* hrow = emb + (size_t)x[tm] * 64;
        short8 ha[2];
        #pragma unroll
        for (int kt = 0; kt < 2; ++kt) {
            const float4* hv = (const float4*)(hrow + kt * 32 + kr);
            const float4 p = hv[0], q = hv[1];
            short8 t;
            t[0] = f2bf(p.x); t[1] = f2bf(p.y); t[2] = f2bf(p.z); t[3] = f2bf(p.w);
            t[4] = f2bf(q.x); t[5] = f2bf(q.y); t[6] = f2bf(q.z); t[7] = f2bf(q.w);
            ha[kt] = t;
        }

        // --- hid_pre = H @ W1 : 8 MFMAs ---
        f32x4 acc[4];
        #pragma unroll
        for (int nt = 0; nt < 4; ++nt) {
            acc[nt] = (f32x4){0.f, 0.f, 0.f, 0.f};
            acc[nt] = __builtin_amdgcn_mfma_f32_16x16x32_bf16(ha[0], fw1[nt],     acc[nt], 0, 0, 0);
            acc[nt] = __builtin_amdgcn_mfma_f32_16x16x32_bf16(ha[1], fw1[4 + nt], acc[nt], 0, 0, 0);
        }

        // --- exact GELU, write bf16 hid to LDS in [m][c] layout ---
        #pragma unroll
        for (int nt = 0; nt < 4; ++nt) {
            #pragma unroll
            for (int i = 0; i < 4; ++i) {
                const float v  = acc[nt][i];
                const float gv = 0.5f * v * (1.0f + erff(v * 0.70710678118f));
                const int  mm  = (lane >> 4) * 4 + i;
                const int  c   = nt * 16 + nco;
                hidb[mm * 72 + c] = f2bf(gv);
            }
        }
        // All 16 lanes-of-group writes must land before cross-lane re-read.
        asm volatile("s_waitcnt lgkmcnt(0)" ::: "memory");

        // --- re-read as A-fragments for the second matmul ---
        short8 pa[2];
        #pragma unroll
        for (int kt = 0; kt < 2; ++kt)
            pa[kt] = *(const short8*)&hidb[(lane & 15) * 72 + kt * 32 + kr];

        // --- corr = gelu(hid) @ W2 : 8 MFMAs ---
        f32x4 acc2[4];
        #pragma unroll
        for (int nt = 0; nt < 4; ++nt) {
            acc2[nt] = (f32x4){0.f, 0.f, 0.f, 0.f};
            acc2[nt] = __builtin_amdgcn_mfma_f32_16x16x32_bf16(pa[0], fw2[nt],     acc2[nt], 0, 0, 0);
            acc2[nt] = __builtin_amdgcn_mfma_f32_16x16x32_bf16(pa[1], fw2[4 + nt], acc2[nt], 0, 0, 0);
        }

        // --- out[t] = h (fp32, exact) + 0.1 * corr ---
        #pragma unroll
        for (int i = 0; i < 4; ++i) {
            const int mm = (lane >> 4) * 4 + i;
            if (mm < rem) {
                const int tt = buck[s0 + mm];
                const float* hr = emb + (size_t)x[tt] * 64;
                float* orow = out + (size_t)tt * 64;
                #pragma unroll
                for (int nt = 0; nt < 4; ++nt) {
                    const int c = nt * 16 + nco;
                    orow[c] = hr[c] + 0.1f * acc2[nt][i];
                }
            }
        }
    }
}

extern "C" void kernel_launch(void* const* d_in, const int* in_sizes, int n_in,
                              void* d_out, int out_size, void* d_ws, size_t ws_size,
                              hipStream_t stream) {
    const int*   x    = (const int*)d_in[0];
    const int*   tdom = (const int*)d_in[1];
    const float* emb  = (const float*)d_in[2];
    const float* W1   = (const float*)d_in[3];
    const float* W2   = (const float*)d_in[4];
    float* out = (float*)d_out;

    int* g_cnt  = (int*)d_ws;
    int* bucket = g_cnt + 16;  // after 64B counter block
    size_t avail_ints = (ws_size > 64) ? (ws_size - 64) / 4 : 0;
    long cap_l = (long)(avail_ints / ND);
    int cap = (cap_l > NTOK) ? NTOK : (int)cap_l;

    hipMemsetAsync(d_ws, 0, ND * sizeof(int), stream);
    hipLaunchKernelGGL(k_bucket_base, dim3(NTOK / 256), dim3(256), 0, stream,
                       x, tdom, emb, out, g_cnt, bucket, cap);
    hipLaunchKernelGGL(k_domain, dim3(ND * NBLK_PER_DOM), dim3(256), 0, stream,
                       x, emb, W1, W2, g_cnt, bucket, cap, out);
}